// Round 11
// baseline (188.341 us; speedup 1.0000x reference)
//
#include <hip/hip_runtime.h>
#include <stdint.h>

// PatchProposalLayer2d: 16x16 sum-pool of (B,1,512,512) fp32 mask, valid = sum<256,
// argmax over fixed JAX threefry uniform(key(42),(B,32,32)) restricted to valid,
// outputs int32 left_h[B], left_w[B] concatenated in d_out.
//
// PRNG (jax_threefry_partitionable=True):
// _threefry_random_bits_partitionable: counts = iota(uint64); threefry_2x32_prf
// binds threefry2x32_p(k1, k2, u32(counts>>32), u32(counts)) -> x = (0, n);
// for bit_width 32 the result is bits1 ^ bits2 (XOR fold; only the 64-bit
// path assembles (bits1<<32)|bits2). uniform = bitcast((bits>>9)|0x3F800000)-1.
//
// Ladder: FAILED original split-iota (R0); (0,n)+b1 (R1); (n,0)+xor (R2);
// (0,n)+b2 (R6); (n,0)+b1 (R8); (n,0)+b2 (R9). THIS ROUND: (0,n)+xor —
// the last partitionable cell and the faithful reading of prng.py.
// (R10 broker-timeout; resubmitting untested.)
#define CTR_LO_FIRST 0   // 1: x=(n,0)  0: x=(0,n)
#define OUT_MODE 2       // 0: b1   1: b2   2: b1^b2

#define H 512
#define W 512
#define PATCH 16
#define HP 32
#define WP 32
#define SPLIT 4              // blocks per batch sample
#define SEG_HP (HP / SPLIT)  // 8 patch rows per segment block
#define THREADS 256

struct Cand { uint32_t key; int idx; };  // key = (bits>>9)+1, 0 = invalid

__device__ __forceinline__ uint32_t rotl32(uint32_t x, int r) {
  return (x << r) | (x >> (32 - r));
}

// threefry2x32 block, key (0,42); returns selected output word combo.
__device__ __forceinline__ uint32_t jax_threefry_bits_part(uint32_t n) {
  const uint32_t k0 = 0u;
  const uint32_t k1 = 42u;
  const uint32_t k2 = 0x1BD11BDAu ^ k0 ^ k1;
#if CTR_LO_FIRST
  uint32_t x0 = n, x1 = 0u;
#else
  uint32_t x0 = 0u, x1 = n;
#endif
  x0 += k0; x1 += k1;
#define TF_RND(r) { x0 += x1; x1 = rotl32(x1, r); x1 ^= x0; }
  TF_RND(13) TF_RND(15) TF_RND(26) TF_RND(6)
  x0 += k1; x1 += k2 + 1u;
  TF_RND(17) TF_RND(29) TF_RND(16) TF_RND(24)
  x0 += k2; x1 += k0 + 2u;
  TF_RND(13) TF_RND(15) TF_RND(26) TF_RND(6)
  x0 += k0; x1 += k1 + 3u;
  TF_RND(17) TF_RND(29) TF_RND(16) TF_RND(24)
  x0 += k1; x1 += k2 + 4u;
  TF_RND(13) TF_RND(15) TF_RND(26) TF_RND(6)
  x0 += k2; x1 += k0 + 5u;
#undef TF_RND
#if OUT_MODE == 0
  return x0;
#elif OUT_MODE == 1
  return x1;
#else
  return x0 ^ x1;
#endif
}

// One block per (batch, segment). Segment = 8 patch rows = 128 image rows.
__global__ __launch_bounds__(THREADS) void patch_seg_kernel(
    const float* __restrict__ mask, Cand* __restrict__ ws) {
  const int blk  = blockIdx.x;
  const int b    = blk / SPLIT;
  const int seg  = blk % SPLIT;
  const int t    = threadIdx.x;
  const int q    = t & 127;   // float4 column within row (0..127)
  const int half = t >> 7;    // 0..1 -> patch rows [half*4, half*4+4)

  __shared__ float part[SEG_HP][128];  // per-(patch-row, float4-col) partials
  __shared__ Cand wave_best[THREADS / 64];

  const float4* img = (const float4*)(mask + (size_t)b * (H * W));

  // Phase 1: coalesced row reads; each thread sums 16 rows of one float4 col
  // for each of its 4 patch rows.
  for (int hl = half * 4; hl < half * 4 + 4; ++hl) {
    const int r0 = seg * (SEG_HP * PATCH) + hl * PATCH;
    float acc = 0.f;
#pragma unroll
    for (int rr = 0; rr < PATCH; ++rr) {
      float4 v = img[(size_t)(r0 + rr) * (W / 4) + q];
      acc += v.x + v.y + v.z + v.w;
    }
    part[hl][q] = acc;
  }
  __syncthreads();

  // Phase 2: one thread per patch of this segment.
  const int hl = t >> 5;       // 0..7
  const int wp = t & 31;       // 0..31
  const float sum = part[hl][wp * 4 + 0] + part[hl][wp * 4 + 1] +
                    part[hl][wp * 4 + 2] + part[hl][wp * 4 + 3];
  int idx = seg * (SEG_HP * WP) + t;   // flat patch index in batch = hp*32+wp
  const uint32_t n = (uint32_t)b * (HP * WP) + (uint32_t)idx;
  const uint32_t bits = jax_threefry_bits_part(n);
  // key: (bits>>9)+1 for valid (strictly monotone in float u), 0 for invalid
  // (matches ordering of where(valid, u, -1.0); u is injective in bits>>9).
  uint32_t key = (sum < 256.0f) ? ((bits >> 9) + 1u) : 0u;

  // Wave butterfly argmax (max key, min idx on tie -> first occurrence).
#pragma unroll
  for (int off = 32; off >= 1; off >>= 1) {
    uint32_t ok = __shfl_xor(key, off);
    int      oi = __shfl_xor(idx, off);
    if (ok > key || (ok == key && oi < idx)) { key = ok; idx = oi; }
  }
  if ((t & 63) == 0) wave_best[t >> 6] = Cand{key, idx};
  __syncthreads();

  if (t == 0) {
    Cand best = wave_best[0];
#pragma unroll
    for (int w = 1; w < THREADS / 64; ++w) {
      Cand c = wave_best[w];
      if (c.key > best.key || (c.key == best.key && c.idx < best.idx))
        best = c;
    }
    ws[blk] = best;
  }
}

// One thread per batch sample: combine SPLIT segment candidates, emit coords.
__global__ void patch_reduce_kernel(const Cand* __restrict__ ws,
                                    int* __restrict__ out, int nB) {
  const int b = blockIdx.x * blockDim.x + threadIdx.x;
  if (b >= nB) return;
  uint32_t key = 0;
  int idx = 1 << 30;
#pragma unroll
  for (int s = 0; s < SPLIT; ++s) {
    Cand c = ws[b * SPLIT + s];
    if (c.key > key || (c.key == key && c.idx < idx)) {
      key = c.key; idx = c.idx;
    }
  }
  out[b]      = (idx / WP) * PATCH;  // left_h
  out[nB + b] = (idx % WP) * PATCH;  // left_w
}

extern "C" void kernel_launch(void* const* d_in, const int* in_sizes, int n_in,
                              void* d_out, int out_size, void* d_ws, size_t ws_size,
                              hipStream_t stream) {
  const float* mask = (const float*)d_in[0];
  int* out = (int*)d_out;
  const int nB = in_sizes[0] / (H * W);  // 128

  Cand* ws = (Cand*)d_ws;  // nB*SPLIT entries = 4 KB

  patch_seg_kernel<<<nB * SPLIT, THREADS, 0, stream>>>(mask, ws);
  patch_reduce_kernel<<<(nB + 127) / 128, 128, 0, stream>>>(ws, out, nB);
}

// Round 17
// 176.457 us; speedup vs baseline: 1.0673x; 1.0673x over previous
//
#include <hip/hip_runtime.h>
#include <stdint.h>

// PatchProposalLayer2d: 16x16 sum-pool of (B,1,512,512) fp32 mask, valid = sum<256,
// argmax over fixed JAX threefry uniform(key(42),(B,32,32)) restricted to valid,
// outputs int32 left_h[B], left_w[B] concatenated in d_out.
//
// PRNG (VERIFIED R11, absmax 0.0): jax_threefry_partitionable=True stream =
// threefry2x32(key=(0,42), x=(hi32(n), lo32(n))=(0,n)), bits = b1 ^ b2.
// uniform = bitcast((bits>>9)|0x3F800000) - 1.0; argmax via monotone key
// (bits>>9)+1 with first-occurrence (min idx) tie-break.
#define CTR_LO_FIRST 0   // x=(0,n)  -- VERIFIED, do not change
#define OUT_MODE 2       // b1^b2    -- VERIFIED, do not change

#define H 512
#define W 512
#define PATCH 16
#define HP 32
#define WP 32
#define SPLIT 16             // blocks per batch sample (R11: 4 -> 16 for TLP)
#define SEG_HP (HP / SPLIT)  // 2 patch rows per segment block
#define THREADS 256

// Native vector type: __builtin_nontemporal_load rejects HIP_vector_type
// (R15 compile error); clang ext_vector_type is layout-identical to float4.
typedef float floatx4 __attribute__((ext_vector_type(4)));

struct Cand { uint32_t key; int idx; };  // key = (bits>>9)+1, 0 = invalid

__device__ __forceinline__ uint32_t rotl32(uint32_t x, int r) {
  return (x << r) | (x >> (32 - r));
}

// threefry2x32 block, key (0,42); verified variant (0,n) + b1^b2.
__device__ __forceinline__ uint32_t jax_threefry_bits_part(uint32_t n) {
  const uint32_t k0 = 0u;
  const uint32_t k1 = 42u;
  const uint32_t k2 = 0x1BD11BDAu ^ k0 ^ k1;
#if CTR_LO_FIRST
  uint32_t x0 = n, x1 = 0u;
#else
  uint32_t x0 = 0u, x1 = n;
#endif
  x0 += k0; x1 += k1;
#define TF_RND(r) { x0 += x1; x1 = rotl32(x1, r); x1 ^= x0; }
  TF_RND(13) TF_RND(15) TF_RND(26) TF_RND(6)
  x0 += k1; x1 += k2 + 1u;
  TF_RND(17) TF_RND(29) TF_RND(16) TF_RND(24)
  x0 += k2; x1 += k0 + 2u;
  TF_RND(13) TF_RND(15) TF_RND(26) TF_RND(6)
  x0 += k0; x1 += k1 + 3u;
  TF_RND(17) TF_RND(29) TF_RND(16) TF_RND(24)
  x0 += k1; x1 += k2 + 4u;
  TF_RND(13) TF_RND(15) TF_RND(26) TF_RND(6)
  x0 += k2; x1 += k0 + 5u;
#undef TF_RND
#if OUT_MODE == 0
  return x0;
#elif OUT_MODE == 1
  return x1;
#else
  return x0 ^ x1;
#endif
}

// One block per (batch, segment). Segment = 2 patch rows = 32 image rows.
// 2048 blocks -> 8 blocks/CU (32 waves/CU): full occupancy for latency hiding.
__global__ __launch_bounds__(THREADS, 8) void patch_seg_kernel(
    const float* __restrict__ mask, Cand* __restrict__ ws) {
  const int blk  = blockIdx.x;
  const int b    = blk / SPLIT;
  const int seg  = blk % SPLIT;
  const int t    = threadIdx.x;
  const int q    = t & 127;   // float4 column within row (0..127)
  const int half = t >> 7;    // patch row 0 or 1 of this segment

  __shared__ float part[SEG_HP][128];  // per-(patch-row, float4-col) partials

  const floatx4* img = (const floatx4*)(mask + (size_t)b * (H * W));

  // Phase 1: each thread sums 16 rows of one float4 column (nontemporal --
  // streaming data, zero reuse).
  {
    const int r0 = seg * (SEG_HP * PATCH) + half * PATCH;
    const floatx4* p = img + (size_t)r0 * (W / 4) + q;
    float acc = 0.f;
#pragma unroll
    for (int rr = 0; rr < PATCH; ++rr) {
      floatx4 v = __builtin_nontemporal_load(p);
      p += (W / 4);
      acc += v.x + v.y + v.z + v.w;
    }
    part[half][q] = acc;
  }
  __syncthreads();

  // Phase 2: wave 0 only -- 64 patches per block = exactly one wave.
  if (t < 64) {
    const int hl = t >> 5;       // 0..1
    const int wp = t & 31;       // 0..31
    const float sum = part[hl][wp * 4 + 0] + part[hl][wp * 4 + 1] +
                      part[hl][wp * 4 + 2] + part[hl][wp * 4 + 3];
    int idx = seg * (SEG_HP * WP) + t;   // flat patch index in batch
    const uint32_t n = (uint32_t)b * (HP * WP) + (uint32_t)idx;
    const uint32_t bits = jax_threefry_bits_part(n);
    uint32_t key = (sum < 256.0f) ? ((bits >> 9) + 1u) : 0u;

    // Wave butterfly argmax (max key, min idx on tie -> first occurrence).
#pragma unroll
    for (int off = 32; off >= 1; off >>= 1) {
      uint32_t ok = __shfl_xor(key, off);
      int      oi = __shfl_xor(idx, off);
      if (ok > key || (ok == key && oi < idx)) { key = ok; idx = oi; }
    }
    if (t == 0) ws[blk] = Cand{key, idx};
  }
}

// One thread per batch sample: combine SPLIT segment candidates, emit coords.
__global__ void patch_reduce_kernel(const Cand* __restrict__ ws,
                                    int* __restrict__ out, int nB) {
  const int b = blockIdx.x * blockDim.x + threadIdx.x;
  if (b >= nB) return;
  uint32_t key = 0;
  int idx = 1 << 30;
#pragma unroll
  for (int s = 0; s < SPLIT; ++s) {
    Cand c = ws[b * SPLIT + s];
    if (c.key > key || (c.key == key && c.idx < idx)) {
      key = c.key; idx = c.idx;
    }
  }
  out[b]      = (idx / WP) * PATCH;  // left_h
  out[nB + b] = (idx % WP) * PATCH;  // left_w
}

extern "C" void kernel_launch(void* const* d_in, const int* in_sizes, int n_in,
                              void* d_out, int out_size, void* d_ws, size_t ws_size,
                              hipStream_t stream) {
  const float* mask = (const float*)d_in[0];
  int* out = (int*)d_out;
  const int nB = in_sizes[0] / (H * W);  // 128

  Cand* ws = (Cand*)d_ws;  // nB*SPLIT entries = 16 KB

  patch_seg_kernel<<<nB * SPLIT, THREADS, 0, stream>>>(mask, ws);
  patch_reduce_kernel<<<(nB + 127) / 128, 128, 0, stream>>>(ws, out, nB);
}